// Round 16
// baseline (832.225 us; speedup 1.0000x reference)
//
#include <hip/hip_runtime.h>
#include <cstdint>
#include <cstddef>

#define L_SEQ 512
#define NBATCH 2
#define NTOK 1024          // B*L
#define E_DIM 1024
#define V_DIM 32000
#define DI_DIM 2048
#define NS_DIM 16
#define DTR_DIM 64
#define DC_DIM 4
#define NL_DIM 4
#define NC 8               // time chunks for parallel scan
#define LC (L_SEQ / NC)    // 64

typedef __bf16 bf16;
typedef __bf16 bf16x8 __attribute__((ext_vector_type(8)));
typedef __bf16 bf16x4 __attribute__((ext_vector_type(4)));
typedef float  f32x4  __attribute__((ext_vector_type(4)));

// async global->LDS, 16B per lane. LDS dest must be wave-uniform base (+lane*16 implicit).
__device__ __forceinline__ void gload_lds16(const void* g, void* l)
{
    __builtin_amdgcn_global_load_lds((const __attribute__((address_space(1))) uint32_t*)g,
                                     (__attribute__((address_space(3))) uint32_t*)l, 16, 0, 0);
}

__device__ __forceinline__ float softplusf(float z)
{
    return fmaxf(z, 0.0f) + log1pf(expf(-fabsf(z)));
}

// ---------------- cast f32 -> bf16 (grid-stride, x4) ----------------
__global__ void cast_f32_to_bf16(const float* __restrict__ in, bf16* __restrict__ out, int n4)
{
    int stride = gridDim.x * blockDim.x;
    for (int i = blockIdx.x * blockDim.x + threadIdx.x; i < n4; i += stride) {
        f32x4 v = ((const f32x4*)in)[i];
        bf16x4 o;
        o[0] = (bf16)v[0]; o[1] = (bf16)v[1]; o[2] = (bf16)v[2]; o[3] = (bf16)v[3];
        ((bf16x4*)out)[i] = o;
    }
}

// fused 3-tensor cast
__global__ void cast3_kernel(const float* __restrict__ a, bf16* __restrict__ oa, int na4,
                             const float* __restrict__ b, bf16* __restrict__ ob, int nb4,
                             const float* __restrict__ c, bf16* __restrict__ oc, int nc4)
{
    int stride = gridDim.x * blockDim.x;
    int tot = na4 + nb4 + nc4;
    for (int i = blockIdx.x * blockDim.x + threadIdx.x; i < tot; i += stride) {
        const float* src; bf16* dst; int k = i;
        if (k < na4) { src = a; dst = oa; }
        else if ((k -= na4) < nb4) { src = b; dst = ob; }
        else { k -= nb4; src = c; dst = oc; }
        f32x4 v = ((const f32x4*)src)[k];
        bf16x4 o;
        o[0] = (bf16)v[0]; o[1] = (bf16)v[1]; o[2] = (bf16)v[2]; o[3] = (bf16)v[3];
        ((bf16x4*)dst)[k] = o;
    }
}

// ---------------- embedding gather ----------------
__global__ void embed_kernel(const int* __restrict__ ids, const float* __restrict__ emb,
                             float* __restrict__ x)
{
    int t = blockIdx.x;
    int id = ids[t];
    ((f32x4*)(x + (size_t)t * E_DIM))[threadIdx.x] =
        ((const f32x4*)(emb + (size_t)id * E_DIM))[threadIdx.x];
}

// ---------------- LayerNorm (row=1024), bf16 out ----------------
__global__ void ln_kernel(const float* __restrict__ x, const float* __restrict__ w,
                          const float* __restrict__ b, bf16* __restrict__ out)
{
    int t = blockIdx.x;
    int tid = threadIdx.x;
    f32x4 v = ((const f32x4*)(x + (size_t)t * E_DIM))[tid];
    float s  = v[0] + v[1] + v[2] + v[3];
    float sq = v[0]*v[0] + v[1]*v[1] + v[2]*v[2] + v[3]*v[3];
#pragma unroll
    for (int off = 1; off < 64; off <<= 1) { s += __shfl_xor(s, off); sq += __shfl_xor(sq, off); }
    __shared__ float ps[4], pq[4];
    if ((tid & 63) == 0) { ps[tid >> 6] = s; pq[tid >> 6] = sq; }
    __syncthreads();
    float S  = ps[0] + ps[1] + ps[2] + ps[3];
    float SQ = pq[0] + pq[1] + pq[2] + pq[3];
    float mu  = S * (1.0f / E_DIM);
    float var = SQ * (1.0f / E_DIM) - mu * mu;
    float rs  = rsqrtf(var + 1e-5f);
    f32x4 wv = ((const f32x4*)w)[tid];
    f32x4 bv = ((const f32x4*)b)[tid];
    bf16x4 o;
#pragma unroll
    for (int i = 0; i < 4; ++i) o[i] = (bf16)((v[i] - mu) * rs * wv[i] + bv[i]);
    ((bf16x4*)(out + (size_t)t * E_DIM))[tid] = o;
}

// swizzle byte-offset within a row: SEGS=4 (64B rows) uses row bits 1-2 (bit0 already
// separates bank halves via 16*row); SEGS=8 (128B rows) uses row bits 0-2.
template<int SEGS>
__device__ __forceinline__ int swz_row(int row)
{
    if constexpr (SEGS == 4) return ((row >> 1) & 3) << 4;
    else                     return (row & 7) << 4;
}

// ---------------- MFMA bf16 GEMM (128-class tiles): C[M,N] = A[M,K] * B[N,K]^T ----------------
// Double-buffered LDS + counted vmcnt (T4). XOR swizzle per rule #21.
// MODE 0: f32 store; MODE 2: bf16 C = softplus(acc + bias[col]);
// MODE 4: bf16 store; MODE 5: atomicAdd into f32 C.
template<int BM, int BN, int BK, int MODE, int SK>
__global__ __launch_bounds__(256) void gemm_bt(const bf16* __restrict__ A, const bf16* __restrict__ B,
                                               void* __restrict__ Cv, int K,
                                               int lda, int ldb, int ldc,
                                               const float* __restrict__ bias,
                                               int RB, int CB, int CBpad)
{
    int pid = blockIdx.x;
    int per = RB * CBpad;
    int sk  = pid / per;
    int rem = pid - sk * per;
    int xcd = rem & 7;
    int j   = rem >> 3;
    int cpx = CBpad >> 3;
    int rb  = j % RB;
    int cb  = xcd * cpx + j / RB;
    if (cb >= CB) return;
    int kseg = K / SK;
    int kbeg = sk * kseg;

    __shared__ __align__(16) bf16 As[2][BM * BK];
    __shared__ __align__(16) bf16 Bs[2][BN * BK];
    int tid  = threadIdx.x;
    int lane = tid & 63;
    int wid  = tid >> 6;
    int wr = wid >> 1, wc = wid & 1;
    int li = lane & 15, lg = lane >> 4;
    const bf16* Ablk = A + (size_t)(rb * BM) * lda;
    const bf16* Bblk = B + (size_t)(cb * BN) * ldb;
    constexpr int MR     = BM / 32;
    constexpr int NR     = BN / 32;
    constexpr int SEGS   = BK / 8;          // 16B segments per row
    constexpr int AOPS   = BM * SEGS;       // lane-ops for A per K-step
    constexpr int TOT    = (BM + BN) * SEGS;
    constexpr int WLOADS = TOT / 256;       // gload_lds per wave per stage
    f32x4 acc[MR][NR] = {};

    auto stage = [&](int buf, int k0) {
#pragma unroll
        for (int it = 0; it < WLOADS; ++it) {
            int wbase = it * 256 + wid * 64;   // wave-uniform
            int idx   = wbase + lane;
            if (wbase < AOPS) {
                int row = idx / SEGS, seg = idx % SEGS;
                int colb = (seg * 16) ^ swz_row<SEGS>(row);
                gload_lds16(Ablk + (size_t)row * lda + k0 + (colb >> 1), &As[buf][(size_t)wbase * 8]);
            } else {
                int bb  = wbase - AOPS;
                int bi  = bb + lane;
                int row = bi / SEGS, seg = bi % SEGS;
                int colb = (seg * 16) ^ swz_row<SEGS>(row);
                gload_lds16(Bblk + (size_t)row * ldb + k0 + (colb >> 1), &Bs[buf][(size_t)bb * 8]);
            }
        }
    };

    int NT = kseg / BK;
    stage(0, kbeg);
    int cur = 0;
    for (int t = 0; t < NT; ++t) {
        if (t + 1 < NT) {
            stage(cur ^ 1, kbeg + (t + 1) * BK);
            asm volatile("s_waitcnt vmcnt(%0)" :: "i"(WLOADS) : "memory");  // current tile landed
        } else {
            asm volatile("s_waitcnt vmcnt(0)" ::: "memory");
        }
        __builtin_amdgcn_sched_barrier(0);
        __builtin_amdgcn_s_barrier();                 // acquire
        __builtin_amdgcn_sched_barrier(0);
#pragma unroll
        for (int kk = 0; kk < BK / 32; ++kk) {
            bf16x8 af[MR], bfr[NR];
#pragma unroll
            for (int m = 0; m < MR; ++m) {
                int rowA = wr * (BM/2) + m * 16 + li;
                int cb2  = (kk * 64 + lg * 16) ^ swz_row<SEGS>(rowA);
                af[m] = *(const bf16x8*)((const char*)As[cur] + (size_t)rowA * (BK * 2) + cb2);
            }
#pragma unroll
            for (int n = 0; n < NR; ++n) {
                int rowB = wc * (BN/2) + n * 16 + li;
                int cb2  = (kk * 64 + lg * 16) ^ swz_row<SEGS>(rowB);
                bfr[n] = *(const bf16x8*)((const char*)Bs[cur] + (size_t)rowB * (BK * 2) + cb2);
            }
            __builtin_amdgcn_s_setprio(1);
#pragma unroll
            for (int m = 0; m < MR; ++m)
#pragma unroll
                for (int n = 0; n < NR; ++n)
                    acc[m][n] = __builtin_amdgcn_mfma_f32_16x16x32_bf16(af[m], bfr[n], acc[m][n], 0, 0, 0);
            __builtin_amdgcn_s_setprio(0);
        }
        __builtin_amdgcn_sched_barrier(0);
        __builtin_amdgcn_s_barrier();                 // release: safe to overwrite buf[cur]
        __builtin_amdgcn_sched_barrier(0);
        cur ^= 1;
    }
    int row0 = rb * BM + wr * (BM/2);
    int col0 = cb * BN + wc * (BN/2);
    float* Cf = (float*)Cv;
    bf16*  Cb = (bf16*)Cv;
#pragma unroll
    for (int m = 0; m < MR; ++m) {
#pragma unroll
        for (int n = 0; n < NR; ++n) {
            int r = row0 + m * 16 + lg * 4;
            int c = col0 + n * 16 + li;
#pragma unroll
            for (int q = 0; q < 4; ++q) {
                float v = acc[m][n][q];
                if (MODE == 0) {
                    Cf[(size_t)(r + q) * ldc + c] = v;
                } else if (MODE == 2) {
                    Cb[(size_t)(r + q) * ldc + c] = (bf16)softplusf(v + bias[c]);
                } else if (MODE == 4) {
                    Cb[(size_t)(r + q) * ldc + c] = (bf16)v;
                } else if (MODE == 5) {
                    atomicAdd(Cf + (size_t)(r + q) * ldc + c, v);
                }
            }
        }
    }
}

template<int BM, int BN, int BK, int MODE, int SK = 1>
static void launch_gemm(const bf16* A, const bf16* B, void* C, int M, int N, int K,
                        int lda, int ldb, int ldc, const float* bias, hipStream_t stream)
{
    int RB = M / BM;
    int CB = (N + BN - 1) / BN;
    int CBpad = (CB + 7) & ~7;
    gemm_bt<BM, BN, BK, MODE, SK><<<RB * CBpad * SK, 256, 0, stream>>>(A, B, C, K, lda, ldb, ldc,
                                                                       bias, RB, CB, CBpad);
}

// ---------------- fused conv+SiLU+x_proj, k-split x2 (512 blocks, 2/CU) ----------------
// block = (4 tokens, one DI-half). Writes u_bf for its cols; partial x_proj into xpart.
__global__ __launch_bounds__(256) void cxk_kernel(
        const bf16* __restrict__ xz, const float* __restrict__ cw,
        const float* __restrict__ cb, const float* __restrict__ xw,
        float* __restrict__ xpart, bf16* __restrict__ u_bf)
{
    int t0  = (blockIdx.x >> 1) * 4;
    int kh  = blockIdx.x & 1;          // DI half: cols [kh*1024, kh*1024+1024)
    int bb  = t0 >> 9;                 // batch index
    int tid = threadIdx.x;
    int f   = tid & 127;
    int ks  = tid >> 7;                // k-split half within block
    __shared__ __align__(16) float sxz[7][256];
    __shared__ __align__(16) float su[4][256];
    __shared__ float pacc[4][128];
    float acc[4] = {0, 0, 0, 0};
    for (int ic = 0; ic < 4; ++ic) {
        int kc = kh * (DI_DIM / 2) + ic * 256;
        __syncthreads();
        if (tid < 224) {
            int row = tid >> 5, c8 = (tid & 31) * 8;
            int tr = t0 - 3 + row;
            float vals[8] = {0, 0, 0, 0, 0, 0, 0, 0};
            if (tr >= bb * L_SEQ) {
                bf16x8 v = *(const bf16x8*)&xz[(size_t)tr * (2 * DI_DIM) + kc + c8];
#pragma unroll
                for (int jj = 0; jj < 8; ++jj) vals[jj] = (float)v[jj];
            }
#pragma unroll
            for (int jj = 0; jj < 8; ++jj) sxz[row][c8 + jj] = vals[jj];
        }
        __syncthreads();
        {
            int c = tid;
            const float* cwp = cw + (size_t)(kc + c) * DC_DIM;
            float w0 = cwp[0], w1 = cwp[1], w2 = cwp[2], w3 = cwp[3];
            float bs = cb[kc + c];
#pragma unroll
            for (int tt = 0; tt < 4; ++tt) {
                float a = bs + w0 * sxz[tt][c] + w1 * sxz[tt + 1][c]
                             + w2 * sxz[tt + 2][c] + w3 * sxz[tt + 3][c];
                float uo = a / (1.0f + __expf(-a));
                su[tt][c] = uo;
                u_bf[(size_t)(t0 + tt) * DI_DIM + kc + c] = (bf16)uo;
            }
        }
        __syncthreads();
        if (f < 96) {
            int kb = ks * 128;
            for (int kk = kb; kk < kb + 128; kk += 4) {
                f32x4 wv = *(const f32x4*)&xw[(size_t)f * DI_DIM + kc + kk];
#pragma unroll
                for (int tt = 0; tt < 4; ++tt) {
                    f32x4 uv = *(f32x4*)&su[tt][kk];
                    acc[tt] += wv[0]*uv[0] + wv[1]*uv[1] + wv[2]*uv[2] + wv[3]*uv[3];
                }
            }
        }
    }
    if (ks == 1 && f < 96) {
#pragma unroll
        for (int tt = 0; tt < 4; ++tt) pacc[tt][f] = acc[tt];
    }
    __syncthreads();
    if (ks == 0 && f < 96) {
#pragma unroll
        for (int tt = 0; tt < 4; ++tt)
            xpart[((size_t)kh * NTOK + t0 + tt) * 128 + f] = acc[tt] + pacc[tt][f];
    }
}

// merge k-split halves -> xdbl (f32) + dt (bf16). grid: NTOK*96/256 = 384.
__global__ void xmerge_kernel(const float* __restrict__ xpart,
                              float* __restrict__ xdbl, bf16* __restrict__ dt_bf)
{
    int i = blockIdx.x * 256 + threadIdx.x;     // < NTOK*96
    int t = i / 96, f = i - t * 96;
    float v = xpart[(size_t)t * 128 + f] + xpart[(size_t)(NTOK + t) * 128 + f];
    xdbl[(size_t)t * 96 + f] = v;
    if (f < 64) dt_bf[(size_t)t * DTR_DIM + f] = (bf16)v;
}

// ---------------- chunked selective scan (delta precomputed, bf16) ----------------
__global__ __launch_bounds__(256) void scan_phase_a(
        const bf16* __restrict__ delta, const float* __restrict__ xdbl,
        const bf16* __restrict__ u_bf, const float* __restrict__ A_log,
        float* __restrict__ Pbuf, float* __restrict__ Sbuf)
{
    int tid = threadIdx.x;
    int c   = blockIdx.x & (NC - 1);
    int dblk= (blockIdx.x >> 3) & 127;
    int b   = blockIdx.x >> 10;
    int d0  = dblk << 4;
    int n = tid & 15, dl = tid >> 4;
    int d = d0 + dl;
    float Ac = -expf(A_log[(size_t)d * NS_DIM + n]);
    float h = 0.0f, P = 1.0f;
    __shared__ float s_dlt[32][16], s_u[32][16], s_B[32][16];
    int tt0 = tid >> 4, cc = tid & 15;
    int tbase = b * L_SEQ + c * LC;
    for (int t0 = 0; t0 < LC; t0 += 32) {
        __syncthreads();
#pragma unroll
        for (int jj = 0; jj < 2; ++jj) {
            int tt = jj * 16 + tt0;
            size_t trow = (size_t)(tbase + t0 + tt);
            s_dlt[tt][cc] = (float)delta[trow * DI_DIM + d0 + cc];
            s_u[tt][cc]   = (float)u_bf[trow * DI_DIM + d0 + cc];
            s_B[tt][cc]   = xdbl[trow * 96 + 64 + cc];
        }
        __syncthreads();
#pragma unroll
        for (int t = 0; t < 32; ++t) {
            float dlt = s_dlt[t][dl];
            float dA  = __expf(dlt * Ac);
            h = fmaf(dA, h, dlt * s_B[t][n] * s_u[t][dl]);
            P *= dA;
        }
    }
    size_t oi = (((size_t)(b * NC + c) * DI_DIM) + d) * NS_DIM + n;
    Pbuf[oi] = P;
    Sbuf[oi] = h;
}

// Phase C with fused chunk-prefix combine.
__global__ __launch_bounds__(256) void scan_phase_c(
        const bf16* __restrict__ delta, const float* __restrict__ xdbl,
        const bf16* __restrict__ u_bf, const bf16* __restrict__ xz,
        const float* __restrict__ A_log, const float* __restrict__ D_par,
        const float* __restrict__ Pbuf, const float* __restrict__ Sbuf,
        bf16* __restrict__ y)
{
    int tid = threadIdx.x;
    int c   = blockIdx.x & (NC - 1);
    int dblk= (blockIdx.x >> 3) & 127;
    int b   = blockIdx.x >> 10;
    int d0  = dblk << 4;
    int n = tid & 15, dl = tid >> 4;
    int d = d0 + dl;
    float Ac = -expf(A_log[(size_t)d * NS_DIM + n]);
    float Dp = D_par[d];
    float h = 0.0f;
    for (int cp = 0; cp < c; ++cp) {
        size_t oi = (((size_t)(b * NC + cp) * DI_DIM) + d) * NS_DIM + n;
        h = fmaf(Pbuf[oi], h, Sbuf[oi]);
    }
    __shared__ float s_dlt[32][16], s_u[32][16], s_res[32][16], s_B[32][16], s_C[32][16];
    __shared__ bf16  s_y[32][16];
    int tt0 = tid >> 4, cc = tid & 15;
    int tbase = b * L_SEQ + c * LC;
    for (int t0 = 0; t0 < LC; t0 += 32) {
        __syncthreads();
#pragma unroll
        for (int jj = 0; jj < 2; ++jj) {
            int tt = jj * 16 + tt0;
            size_t trow = (size_t)(tbase + t0 + tt);
            s_dlt[tt][cc] = (float)delta[trow * DI_DIM + d0 + cc];
            s_u[tt][cc]   = (float)u_bf[trow * DI_DIM + d0 + cc];
            s_res[tt][cc] = (float)xz[trow * (2 * DI_DIM) + DI_DIM + d0 + cc];
            s_B[tt][cc]   = xdbl[trow * 96 + 64 + cc];
            s_C[tt][cc]   = xdbl[trow * 96 + 80 + cc];
        }
        __syncthreads();
#pragma unroll
        for (int t = 0; t < 32; ++t) {
            float dlt = s_dlt[t][dl];
            float uu  = s_u[t][dl];
            float dA  = __expf(dlt * Ac);
            float dBu = dlt * s_B[t][n] * uu;
            h = fmaf(dA, h, dBu);
            float yp = h * s_C[t][n];
            yp += __shfl_xor(yp, 1);
            yp += __shfl_xor(yp, 2);
            yp += __shfl_xor(yp, 4);
            yp += __shfl_xor(yp, 8);
            if (n == 0) {
                float res = s_res[t][dl];
                float yv  = fmaf(uu, Dp, yp) * (res / (1.0f + __expf(-res)));
                s_y[t][dl] = (bf16)yv;
            }
        }
        __syncthreads();
#pragma unroll
        for (int jj = 0; jj < 2; ++jj) {
            int tt = jj * 16 + tt0;
            size_t trow = (size_t)(tbase + t0 + tt);
            y[trow * DI_DIM + d0 + cc] = s_y[tt][cc];
        }
    }
}

// ---------------- per-token online logsumexp + NLL + loss atomic (single pass) ----------------
__global__ void lse_nll_kernel(const float* __restrict__ logits, const int* __restrict__ targets,
                               float* __restrict__ lossp)
{
    int t = blockIdx.x, tid = threadIdx.x;
    const f32x4* row = (const f32x4*)(logits + (size_t)t * V_DIM);
    float m = -1e30f, s = 0.0f;
    for (int i = tid; i < V_DIM / 4; i += 256) {
        f32x4 v = row[i];
        float m4 = fmaxf(fmaxf(v[0], v[1]), fmaxf(v[2], v[3]));
        if (m4 > m) { s *= __expf(m - m4); m = m4; }
        s += __expf(v[0] - m) + __expf(v[1] - m) + __expf(v[2] - m) + __expf(v[3] - m);
    }
#pragma unroll
    for (int off = 1; off < 64; off <<= 1) {
        float mo = __shfl_xor(m, off), so = __shfl_xor(s, off);
        float nm = fmaxf(m, mo);
        s = s * __expf(m - nm) + so * __expf(mo - nm);
        m = nm;
    }
    __shared__ float pm[4], ps2[4];
    if ((tid & 63) == 0) { pm[tid >> 6] = m; ps2[tid >> 6] = s; }
    __syncthreads();
    if (tid == 0) {
        float M = fmaxf(fmaxf(pm[0], pm[1]), fmaxf(pm[2], pm[3]));
        float S = ps2[0] * __expf(pm[0] - M) + ps2[1] * __expf(pm[1] - M)
                + ps2[2] * __expf(pm[2] - M) + ps2[3] * __expf(pm[3] - M);
        int tg = targets[t];
        if (tg >= 0) {
            float v = (M + logf(S)) - logits[(size_t)t * V_DIM + tg];
            atomicAdd(lossp, v * (1.0f / NTOK));
        }
    }
}

// ---------------- host launcher ----------------
extern "C" void kernel_launch(void* const* d_in, const int* in_sizes, int n_in,
                              void* d_out, int out_size, void* d_ws, size_t ws_size,
                              hipStream_t stream)
{
    const int*   ids   = (const int*)d_in[0];
    const int*   tgt   = (const int*)d_in[1];
    const float* emb   = (const float*)d_in[2];
    const float* ln_w  = (const float*)d_in[3];
    const float* ln_b  = (const float*)d_in[4];
    const float* inw   = (const float*)d_in[5];
    const float* convw = (const float*)d_in[6];
    const float* convb = (const float*)d_in[7];
    const float* xw    = (const float*)d_in[8];
    const float* dtw   = (const float*)d_in[9];
    const float* dtb   = (const float*)d_in[10];
    const float* alog  = (const float*)d_in[11];
    const float* dpar  = (const float*)d_in[12];
    const float* outw  = (const float*)d_in[13];
    const float* flnw  = (const float*)d_in[14];
    const float* flnb  = (const float*)d_in[15];
    float* logits = (float*)d_out;
    float* lossp  = logits + (size_t)NTOK * V_DIM;

    const size_t INW_L  = (size_t)2 * DI_DIM * E_DIM;
    const size_t OUTW_L = (size_t)E_DIM * DI_DIM;
    const size_t DTW_L  = (size_t)DI_DIM * DTR_DIM;

    char* wsp = (char*)d_ws;
    size_t off = 0;
    auto alloc = [&](size_t bytes) -> void* {
        void* p = wsp + off;
        off += (bytes + 255) & ~(size_t)255;
        return p;
    };
    bf16*  emb_bf  = (bf16*)alloc((size_t)V_DIM * E_DIM * 2);
    float* x       = (float*)alloc((size_t)NTOK * E_DIM * 4);
    bf16*  h_bf    = (bf16*)alloc((size_t)NTOK * E_DIM * 2);
    bf16*  xzb     = (bf16*)alloc((size_t)NTOK * 2 * DI_DIM * 2);
    bf16*  u_bf    = (bf16*)alloc((size_t)NTOK * DI_DIM * 2);
    float* xdbl    = (float*)alloc((size_t)NTOK * 96 * 4);
    float* xpart   = (float*)alloc((size_t)2 * NTOK * 128 * 4);     // 1 MB
    bf16*  dt_bf   = (bf16*)alloc((size_t)NTOK * DTR_DIM * 2);
    bf16*  deltab  = (bf16*)alloc((size_t)NTOK * DI_DIM * 2);
    bf16*  y_bf    = (bf16*)alloc((size_t)NTOK * DI_DIM * 2);
    bf16*  xf_bf   = (bf16*)alloc((size_t)NTOK * E_DIM * 2);
    float* Pbuf    = (float*)alloc((size_t)NBATCH * NC * DI_DIM * NS_DIM * 4);
    float* Sbuf    = (float*)alloc((size_t)NBATCH * NC * DI_DIM * NS_DIM * 4);
    size_t base = off;
    size_t big_need = base + (((size_t)NL_DIM * INW_L * 2 + 255) & ~(size_t)255)
                           + (((size_t)NL_DIM * OUTW_L * 2 + 255) & ~(size_t)255)
                           + (((size_t)NL_DIM * DTW_L * 2 + 255) & ~(size_t)255);
    bool big = (big_need <= ws_size);
    bf16* winl; bf16* woutl; bf16* wdtl;
    if (big) {
        winl  = (bf16*)alloc((size_t)NL_DIM * INW_L * 2);
        woutl = (bf16*)alloc((size_t)NL_DIM * OUTW_L * 2);
        wdtl  = (bf16*)alloc((size_t)NL_DIM * DTW_L * 2);
    } else {
        winl  = (bf16*)alloc(INW_L * 2);
        woutl = (bf16*)alloc(OUTW_L * 2);
        wdtl  = (bf16*)alloc(DTW_L * 2);
    }
    if (off > ws_size) return;

    hipMemsetAsync(lossp, 0, sizeof(float), stream);
    {
        int n4 = (int)((size_t)V_DIM * E_DIM / 4);
        cast_f32_to_bf16<<<4096, 256, 0, stream>>>(emb, emb_bf, n4);
    }
    if (big) {
        cast3_kernel<<<4096, 256, 0, stream>>>(
            inw,  winl,  (int)((size_t)NL_DIM * INW_L / 4),
            outw, woutl, (int)((size_t)NL_DIM * OUTW_L / 4),
            dtw,  wdtl,  (int)((size_t)NL_DIM * DTW_L / 4));
    }
    embed_kernel<<<NTOK, 256, 0, stream>>>(ids, emb, x);

    for (int l = 0; l < NL_DIM; ++l) {
        const bf16* wi = big ? winl  + (size_t)l * INW_L  : winl;
        const bf16* wo = big ? woutl + (size_t)l * OUTW_L : woutl;
        const bf16* wd = big ? wdtl  + (size_t)l * DTW_L  : wdtl;
        if (!big) {
            cast3_kernel<<<2048, 256, 0, stream>>>(
                inw  + (size_t)l * INW_L,  winl,  (int)(INW_L / 4),
                outw + (size_t)l * OUTW_L, woutl, (int)(OUTW_L / 4),
                dtw  + (size_t)l * DTW_L,  wdtl,  (int)(DTW_L / 4));
        }
        ln_kernel<<<NTOK, 256, 0, stream>>>(x, ln_w + l * E_DIM, ln_b + l * E_DIM, h_bf);
        // xz[1024,4096] = h @ in_w^T  (bf16 out, BK=32, dbuf+counted vmcnt)
        launch_gemm<128, 64, 32, 4>(h_bf, wi, xzb, NTOK, 2 * DI_DIM, E_DIM,
                                    E_DIM, E_DIM, 2 * DI_DIM, nullptr, stream);
        // fused conv+silu+x_proj  (k-split x2: 512 blocks) + merge
        cxk_kernel<<<NTOK / 2, 256, 0, stream>>>(
            xzb, convw + (size_t)l * DI_DIM * DC_DIM, convb + (size_t)l * DI_DIM,
            xw + (size_t)l * 96 * DI_DIM, xpart, u_bf);
        xmerge_kernel<<<NTOK * 96 / 256, 256, 0, stream>>>(xpart, xdbl, dt_bf);
        // delta = softplus(dt @ dtw^T + dtb) (bf16 out)
        launch_gemm<64, 64, 32, 2>(dt_bf, wd, deltab, NTOK, DI_DIM, DTR_DIM,
                                   DTR_DIM, DTR_DIM, DI_DIM, dtb + (size_t)l * DI_DIM, stream);
        scan_phase_a<<<NBATCH * (DI_DIM / 16) * NC, 256, 0, stream>>>(
            deltab, xdbl, u_bf, alog + (size_t)l * DI_DIM * NS_DIM, Pbuf, Sbuf);
        scan_phase_c<<<NBATCH * (DI_DIM / 16) * NC, 256, 0, stream>>>(
            deltab, xdbl, u_bf, xzb, alog + (size_t)l * DI_DIM * NS_DIM,
            dpar + (size_t)l * DI_DIM, Pbuf, Sbuf, y_bf);
        // x += y @ out_w^T  (split-K 8x -> 512 blocks, 2/CU)
        launch_gemm<128, 128, 32, 5, 8>(y_bf, wo, x, NTOK, E_DIM, DI_DIM,
                                        DI_DIM, DI_DIM, E_DIM, nullptr, stream);
    }
    ln_kernel<<<NTOK, 256, 0, stream>>>(x, flnw, flnb, xf_bf);
    // logits = x_f @ emb^T  (128x128 dbuf template: 4 blocks/CU vs 256^2 kernel's 1)
    launch_gemm<128, 128, 32, 0>(xf_bf, emb_bf, logits, NTOK, V_DIM, E_DIM,
                                 E_DIM, E_DIM, V_DIM, nullptr, stream);
    lse_nll_kernel<<<NTOK, 256, 0, stream>>>(logits, tgt, lossp);
}

// Round 17
// 826.251 us; speedup vs baseline: 1.0072x; 1.0072x over previous
//
#include <hip/hip_runtime.h>
#include <cstdint>
#include <cstddef>

#define L_SEQ 512
#define NBATCH 2
#define NTOK 1024          // B*L
#define E_DIM 1024
#define V_DIM 32000
#define DI_DIM 2048
#define NS_DIM 16
#define DTR_DIM 64
#define DC_DIM 4
#define NL_DIM 4
#define NC 8               // time chunks for parallel scan
#define LC (L_SEQ / NC)    // 64

typedef __bf16 bf16;
typedef __bf16 bf16x8 __attribute__((ext_vector_type(8)));
typedef __bf16 bf16x4 __attribute__((ext_vector_type(4)));
typedef float  f32x4  __attribute__((ext_vector_type(4)));

// async global->LDS, 16B per lane. LDS dest must be wave-uniform base (+lane*16 implicit).
__device__ __forceinline__ void gload_lds16(const void* g, void* l)
{
    __builtin_amdgcn_global_load_lds((const __attribute__((address_space(1))) uint32_t*)g,
                                     (__attribute__((address_space(3))) uint32_t*)l, 16, 0, 0);
}

__device__ __forceinline__ float softplusf(float z)
{
    return fmaxf(z, 0.0f) + log1pf(expf(-fabsf(z)));
}

// ---------------- cast f32 -> bf16 (grid-stride, x4) ----------------
__global__ void cast_f32_to_bf16(const float* __restrict__ in, bf16* __restrict__ out, int n4)
{
    int stride = gridDim.x * blockDim.x;
    for (int i = blockIdx.x * blockDim.x + threadIdx.x; i < n4; i += stride) {
        f32x4 v = ((const f32x4*)in)[i];
        bf16x4 o;
        o[0] = (bf16)v[0]; o[1] = (bf16)v[1]; o[2] = (bf16)v[2]; o[3] = (bf16)v[3];
        ((bf16x4*)out)[i] = o;
    }
}

// fused 3-tensor cast
__global__ void cast3_kernel(const float* __restrict__ a, bf16* __restrict__ oa, int na4,
                             const float* __restrict__ b, bf16* __restrict__ ob, int nb4,
                             const float* __restrict__ c, bf16* __restrict__ oc, int nc4)
{
    int stride = gridDim.x * blockDim.x;
    int tot = na4 + nb4 + nc4;
    for (int i = blockIdx.x * blockDim.x + threadIdx.x; i < tot; i += stride) {
        const float* src; bf16* dst; int k = i;
        if (k < na4) { src = a; dst = oa; }
        else if ((k -= na4) < nb4) { src = b; dst = ob; }
        else { k -= nb4; src = c; dst = oc; }
        f32x4 v = ((const f32x4*)src)[k];
        bf16x4 o;
        o[0] = (bf16)v[0]; o[1] = (bf16)v[1]; o[2] = (bf16)v[2]; o[3] = (bf16)v[3];
        ((bf16x4*)dst)[k] = o;
    }
}

// ---------------- embedding gather ----------------
__global__ void embed_kernel(const int* __restrict__ ids, const float* __restrict__ emb,
                             float* __restrict__ x)
{
    int t = blockIdx.x;
    int id = ids[t];
    ((f32x4*)(x + (size_t)t * E_DIM))[threadIdx.x] =
        ((const f32x4*)(emb + (size_t)id * E_DIM))[threadIdx.x];
}

// ---------------- LayerNorm (row=1024), bf16 out ----------------
__global__ void ln_kernel(const float* __restrict__ x, const float* __restrict__ w,
                          const float* __restrict__ b, bf16* __restrict__ out)
{
    int t = blockIdx.x;
    int tid = threadIdx.x;
    f32x4 v = ((const f32x4*)(x + (size_t)t * E_DIM))[tid];
    float s  = v[0] + v[1] + v[2] + v[3];
    float sq = v[0]*v[0] + v[1]*v[1] + v[2]*v[2] + v[3]*v[3];
#pragma unroll
    for (int off = 1; off < 64; off <<= 1) { s += __shfl_xor(s, off); sq += __shfl_xor(sq, off); }
    __shared__ float ps[4], pq[4];
    if ((tid & 63) == 0) { ps[tid >> 6] = s; pq[tid >> 6] = sq; }
    __syncthreads();
    float S  = ps[0] + ps[1] + ps[2] + ps[3];
    float SQ = pq[0] + pq[1] + pq[2] + pq[3];
    float mu  = S * (1.0f / E_DIM);
    float var = SQ * (1.0f / E_DIM) - mu * mu;
    float rs  = rsqrtf(var + 1e-5f);
    f32x4 wv = ((const f32x4*)w)[tid];
    f32x4 bv = ((const f32x4*)b)[tid];
    bf16x4 o;
#pragma unroll
    for (int i = 0; i < 4; ++i) o[i] = (bf16)((v[i] - mu) * rs * wv[i] + bv[i]);
    ((bf16x4*)(out + (size_t)t * E_DIM))[tid] = o;
}

// swizzle byte-offset within a row: SEGS=4 (64B rows) uses row bits 1-2 (bit0 already
// separates bank halves via 16*row); SEGS=8 (128B rows) uses row bits 0-2.
template<int SEGS>
__device__ __forceinline__ int swz_row(int row)
{
    if constexpr (SEGS == 4) return ((row >> 1) & 3) << 4;
    else                     return (row & 7) << 4;
}

// ---------------- MFMA bf16 GEMM (128-class tiles): C[M,N] = A[M,K] * B[N,K]^T ----------------
// Double-buffered LDS + counted vmcnt (T4). XOR swizzle per rule #21.
// MODE 0: f32 store; MODE 2: bf16 C = softplus(acc + bias[col]);
// MODE 4: bf16 store; MODE 5: atomicAdd into f32 C.
template<int BM, int BN, int BK, int MODE, int SK>
__global__ __launch_bounds__(256) void gemm_bt(const bf16* __restrict__ A, const bf16* __restrict__ B,
                                               void* __restrict__ Cv, int K,
                                               int lda, int ldb, int ldc,
                                               const float* __restrict__ bias,
                                               int RB, int CB, int CBpad)
{
    int pid = blockIdx.x;
    int per = RB * CBpad;
    int sk  = pid / per;
    int rem = pid - sk * per;
    int xcd = rem & 7;
    int j   = rem >> 3;
    int cpx = CBpad >> 3;
    int rb  = j % RB;
    int cb  = xcd * cpx + j / RB;
    if (cb >= CB) return;
    int kseg = K / SK;
    int kbeg = sk * kseg;

    __shared__ __align__(16) bf16 As[2][BM * BK];
    __shared__ __align__(16) bf16 Bs[2][BN * BK];
    int tid  = threadIdx.x;
    int lane = tid & 63;
    int wid  = tid >> 6;
    int wr = wid >> 1, wc = wid & 1;
    int li = lane & 15, lg = lane >> 4;
    const bf16* Ablk = A + (size_t)(rb * BM) * lda;
    const bf16* Bblk = B + (size_t)(cb * BN) * ldb;
    constexpr int MR     = BM / 32;
    constexpr int NR     = BN / 32;
    constexpr int SEGS   = BK / 8;          // 16B segments per row
    constexpr int AOPS   = BM * SEGS;       // lane-ops for A per K-step
    constexpr int TOT    = (BM + BN) * SEGS;
    constexpr int WLOADS = TOT / 256;       // gload_lds per wave per stage
    f32x4 acc[MR][NR] = {};

    auto stage = [&](int buf, int k0) {
#pragma unroll
        for (int it = 0; it < WLOADS; ++it) {
            int wbase = it * 256 + wid * 64;   // wave-uniform
            int idx   = wbase + lane;
            if (wbase < AOPS) {
                int row = idx / SEGS, seg = idx % SEGS;
                int colb = (seg * 16) ^ swz_row<SEGS>(row);
                gload_lds16(Ablk + (size_t)row * lda + k0 + (colb >> 1), &As[buf][(size_t)wbase * 8]);
            } else {
                int bb  = wbase - AOPS;
                int bi  = bb + lane;
                int row = bi / SEGS, seg = bi % SEGS;
                int colb = (seg * 16) ^ swz_row<SEGS>(row);
                gload_lds16(Bblk + (size_t)row * ldb + k0 + (colb >> 1), &Bs[buf][(size_t)bb * 8]);
            }
        }
    };

    int NT = kseg / BK;
    stage(0, kbeg);
    int cur = 0;
    for (int t = 0; t < NT; ++t) {
        if (t + 1 < NT) {
            stage(cur ^ 1, kbeg + (t + 1) * BK);
            asm volatile("s_waitcnt vmcnt(%0)" :: "i"(WLOADS) : "memory");  // current tile landed
        } else {
            asm volatile("s_waitcnt vmcnt(0)" ::: "memory");
        }
        __builtin_amdgcn_sched_barrier(0);
        __builtin_amdgcn_s_barrier();                 // acquire
        __builtin_amdgcn_sched_barrier(0);
#pragma unroll
        for (int kk = 0; kk < BK / 32; ++kk) {
            bf16x8 af[MR], bfr[NR];
#pragma unroll
            for (int m = 0; m < MR; ++m) {
                int rowA = wr * (BM/2) + m * 16 + li;
                int cb2  = (kk * 64 + lg * 16) ^ swz_row<SEGS>(rowA);
                af[m] = *(const bf16x8*)((const char*)As[cur] + (size_t)rowA * (BK * 2) + cb2);
            }
#pragma unroll
            for (int n = 0; n < NR; ++n) {
                int rowB = wc * (BN/2) + n * 16 + li;
                int cb2  = (kk * 64 + lg * 16) ^ swz_row<SEGS>(rowB);
                bfr[n] = *(const bf16x8*)((const char*)Bs[cur] + (size_t)rowB * (BK * 2) + cb2);
            }
            __builtin_amdgcn_s_setprio(1);
#pragma unroll
            for (int m = 0; m < MR; ++m)
#pragma unroll
                for (int n = 0; n < NR; ++n)
                    acc[m][n] = __builtin_amdgcn_mfma_f32_16x16x32_bf16(af[m], bfr[n], acc[m][n], 0, 0, 0);
            __builtin_amdgcn_s_setprio(0);
        }
        __builtin_amdgcn_sched_barrier(0);
        __builtin_amdgcn_s_barrier();                 // release: safe to overwrite buf[cur]
        __builtin_amdgcn_sched_barrier(0);
        cur ^= 1;
    }
    int row0 = rb * BM + wr * (BM/2);
    int col0 = cb * BN + wc * (BN/2);
    float* Cf = (float*)Cv;
    bf16*  Cb = (bf16*)Cv;
#pragma unroll
    for (int m = 0; m < MR; ++m) {
#pragma unroll
        for (int n = 0; n < NR; ++n) {
            int r = row0 + m * 16 + lg * 4;
            int c = col0 + n * 16 + li;
#pragma unroll
            for (int q = 0; q < 4; ++q) {
                float v = acc[m][n][q];
                if (MODE == 0) {
                    Cf[(size_t)(r + q) * ldc + c] = v;
                } else if (MODE == 2) {
                    Cb[(size_t)(r + q) * ldc + c] = (bf16)softplusf(v + bias[c]);
                } else if (MODE == 4) {
                    Cb[(size_t)(r + q) * ldc + c] = (bf16)v;
                } else if (MODE == 5) {
                    atomicAdd(Cf + (size_t)(r + q) * ldc + c, v);
                }
            }
        }
    }
}

template<int BM, int BN, int BK, int MODE, int SK = 1>
static void launch_gemm(const bf16* A, const bf16* B, void* C, int M, int N, int K,
                        int lda, int ldb, int ldc, const float* bias, hipStream_t stream)
{
    int RB = M / BM;
    int CB = (N + BN - 1) / BN;
    int CBpad = (CB + 7) & ~7;
    gemm_bt<BM, BN, BK, MODE, SK><<<RB * CBpad * SK, 256, 0, stream>>>(A, B, C, K, lda, ldb, ldc,
                                                                       bias, RB, CB, CBpad);
}

// ---------------- 256x256 logits GEMM: 8 waves, BK=64 dbuf, 3-bit swizzle, counted vmcnt ----------------
// Measured best at this shape: ~96 us, 0 bank conflicts (VGPR-bound 2 waves/SIMD;
// the 128^2 template A/B'd at 106 us despite 36% occupancy — per-tile efficiency wins).
__global__ __launch_bounds__(512) void gemm256_logits(const bf16* __restrict__ A,
                                                      const bf16* __restrict__ B,
                                                      float* __restrict__ C)
{
    int pid = blockIdx.x;
    int x = pid & 7, i = pid >> 3;          // XCD-chunked bijective map over 4x125 tiles
    int cbq = (x < 5) ? 16 : 15;
    int ci = i >> 2;
    if (ci >= cbq) return;                  // whole block exits -> no barrier mismatch
    int cb = (x < 5) ? x * 16 + ci : 80 + (x - 5) * 15 + ci;
    int rb = i & 3;

    __shared__ __align__(16) bf16 Abuf[2][256 * 64];   // 32KB each
    __shared__ __align__(16) bf16 Bbuf[2][256 * 64];
    int tid  = threadIdx.x;
    int lane = tid & 63, wid = tid >> 6;
    int wr = wid >> 2, wc = wid & 3;        // 2x4 wave grid, 128x64 per wave
    int li = lane & 15, lg = lane >> 4;
    const bf16* Ablk = A + (size_t)(rb * 256) * E_DIM;
    const bf16* Bblk = B + (size_t)(cb * 256) * E_DIM;

    f32x4 acc[8][4] = {};

    auto stage = [&](int buf, int k0) {     // 8 gload_lds per wave (4 A + 4 B)
#pragma unroll
        for (int sw = 0; sw < 4; ++sw) {
            int wb  = sw * 8192 + wid * 1024;
            int y   = wb + lane * 16;
            int row = y >> 7;
            int colb = (y & 127) ^ ((row & 7) << 4);
            gload_lds16(Ablk + (size_t)row * E_DIM + k0 + (colb >> 1),
                        (char*)Abuf[buf] + wb);
        }
#pragma unroll
        for (int sw = 0; sw < 4; ++sw) {
            int wb  = sw * 8192 + wid * 1024;
            int y   = wb + lane * 16;
            int row = y >> 7;
            int colb = (y & 127) ^ ((row & 7) << 4);
            gload_lds16(Bblk + (size_t)row * E_DIM + k0 + (colb >> 1),
                        (char*)Bbuf[buf] + wb);
        }
    };

    stage(0, 0);
    int cur = 0;
    for (int t = 0; t < 16; ++t) {
        if (t + 1 < 16) {
            stage(cur ^ 1, (t + 1) * 64);              // 8 new loads in flight
            asm volatile("s_waitcnt vmcnt(8)" ::: "memory");   // current tile's 8 landed
        } else {
            asm volatile("s_waitcnt vmcnt(0)" ::: "memory");
        }
        __builtin_amdgcn_sched_barrier(0);
        __builtin_amdgcn_s_barrier();                  // acquire
        __builtin_amdgcn_sched_barrier(0);
        const char* Ab = (const char*)Abuf[cur];
        const char* Bb = (const char*)Bbuf[cur];
#pragma unroll
        for (int kk = 0; kk < 2; ++kk) {
            bf16x8 af[8], bfr[4];
#pragma unroll
            for (int m = 0; m < 8; ++m) {
                int row = wr * 128 + m * 16 + li;
                int ab  = (row << 7) + ((kk * 64 + lg * 16) ^ ((row & 7) << 4));
                af[m] = *(const bf16x8*)(Ab + ab);
            }
#pragma unroll
            for (int n = 0; n < 4; ++n) {
                int row = wc * 64 + n * 16 + li;
                int bb  = (row << 7) + ((kk * 64 + lg * 16) ^ ((row & 7) << 4));
                bfr[n] = *(const bf16x8*)(Bb + bb);
            }
            __builtin_amdgcn_s_setprio(1);
#pragma unroll
            for (int m = 0; m < 8; ++m)
#pragma unroll
                for (int n = 0; n < 4; ++n)
                    acc[m][n] = __builtin_amdgcn_mfma_f32_16x16x32_bf16(af[m], bfr[n], acc[m][n], 0, 0, 0);
            __builtin_amdgcn_s_setprio(0);
        }
        __builtin_amdgcn_sched_barrier(0);
        __builtin_amdgcn_s_barrier();                  // release: safe to overwrite buf[cur]
        __builtin_amdgcn_sched_barrier(0);
        cur ^= 1;
    }
    int row0 = rb * 256 + wr * 128;
    int col0 = cb * 256 + wc * 64;
#pragma unroll
    for (int m = 0; m < 8; ++m) {
#pragma unroll
        for (int n = 0; n < 4; ++n) {
            int r = row0 + m * 16 + lg * 4;
            int c = col0 + n * 16 + li;
#pragma unroll
            for (int q = 0; q < 4; ++q)
                C[(size_t)(r + q) * V_DIM + c] = acc[m][n][q];
        }
    }
}

// ---------------- fused conv+SiLU+x_proj, k-split x2 (512 blocks, 2/CU) ----------------
// block = (4 tokens, one DI-half). Writes u_bf for its cols; partial x_proj into xpart.
__global__ __launch_bounds__(256) void cxk_kernel(
        const bf16* __restrict__ xz, const float* __restrict__ cw,
        const float* __restrict__ cb, const float* __restrict__ xw,
        float* __restrict__ xpart, bf16* __restrict__ u_bf)
{
    int t0  = (blockIdx.x >> 1) * 4;
    int kh  = blockIdx.x & 1;          // DI half: cols [kh*1024, kh*1024+1024)
    int bb  = t0 >> 9;                 // batch index
    int tid = threadIdx.x;
    int f   = tid & 127;
    int ks  = tid >> 7;                // k-split half within block
    __shared__ __align__(16) float sxz[7][256];
    __shared__ __align__(16) float su[4][256];
    __shared__ float pacc[4][128];
    float acc[4] = {0, 0, 0, 0};
    for (int ic = 0; ic < 4; ++ic) {
        int kc = kh * (DI_DIM / 2) + ic * 256;
        __syncthreads();
        if (tid < 224) {
            int row = tid >> 5, c8 = (tid & 31) * 8;
            int tr = t0 - 3 + row;
            float vals[8] = {0, 0, 0, 0, 0, 0, 0, 0};
            if (tr >= bb * L_SEQ) {
                bf16x8 v = *(const bf16x8*)&xz[(size_t)tr * (2 * DI_DIM) + kc + c8];
#pragma unroll
                for (int jj = 0; jj < 8; ++jj) vals[jj] = (float)v[jj];
            }
#pragma unroll
            for (int jj = 0; jj < 8; ++jj) sxz[row][c8 + jj] = vals[jj];
        }
        __syncthreads();
        {
            int c = tid;
            const float* cwp = cw + (size_t)(kc + c) * DC_DIM;
            float w0 = cwp[0], w1 = cwp[1], w2 = cwp[2], w3 = cwp[3];
            float bs = cb[kc + c];
#pragma unroll
            for (int tt = 0; tt < 4; ++tt) {
                float a = bs + w0 * sxz[tt][c] + w1 * sxz[tt + 1][c]
                             + w2 * sxz[tt + 2][c] + w3 * sxz[tt + 3][c];
                float uo = a / (1.0f + __expf(-a));
                su[tt][c] = uo;
                u_bf[(size_t)(t0 + tt) * DI_DIM + kc + c] = (bf16)uo;
            }
        }
        __syncthreads();
        if (f < 96) {
            int kb = ks * 128;
            for (int kk = kb; kk < kb + 128; kk += 4) {
                f32x4 wv = *(const f32x4*)&xw[(size_t)f * DI_DIM + kc + kk];
#pragma unroll
                for (int tt = 0; tt < 4; ++tt) {
                    f32x4 uv = *(f32x4*)&su[tt][kk];
                    acc[tt] += wv[0]*uv[0] + wv[1]*uv[1] + wv[2]*uv[2] + wv[3]*uv[3];
                }
            }
        }
    }
    if (ks == 1 && f < 96) {
#pragma unroll
        for (int tt = 0; tt < 4; ++tt) pacc[tt][f] = acc[tt];
    }
    __syncthreads();
    if (ks == 0 && f < 96) {
#pragma unroll
        for (int tt = 0; tt < 4; ++tt)
            xpart[((size_t)kh * NTOK + t0 + tt) * 128 + f] = acc[tt] + pacc[tt][f];
    }
}

// merge k-split halves -> xdbl (f32) + dt (bf16). grid: NTOK*96/256 = 384.
__global__ void xmerge_kernel(const float* __restrict__ xpart,
                              float* __restrict__ xdbl, bf16* __restrict__ dt_bf)
{
    int i = blockIdx.x * 256 + threadIdx.x;     // < NTOK*96
    int t = i / 96, f = i - t * 96;
    float v = xpart[(size_t)t * 128 + f] + xpart[(size_t)(NTOK + t) * 128 + f];
    xdbl[(size_t)t * 96 + f] = v;
    if (f < 64) dt_bf[(size_t)t * DTR_DIM + f] = (bf16)v;
}

// ---------------- chunked selective scan (delta precomputed, bf16) ----------------
__global__ __launch_bounds__(256) void scan_phase_a(
        const bf16* __restrict__ delta, const float* __restrict__ xdbl,
        const bf16* __restrict__ u_bf, const float* __restrict__ A_log,
        float* __restrict__ Pbuf, float* __restrict__ Sbuf)
{
    int tid = threadIdx.x;
    int c   = blockIdx.x & (NC - 1);
    int dblk= (blockIdx.x >> 3) & 127;
    int b   = blockIdx.x >> 10;
    int d0  = dblk << 4;
    int n = tid & 15, dl = tid >> 4;
    int d = d0 + dl;
    float Ac = -expf(A_log[(size_t)d * NS_DIM + n]);
    float h = 0.0f, P = 1.0f;
    __shared__ float s_dlt[32][16], s_u[32][16], s_B[32][16];
    int tt0 = tid >> 4, cc = tid & 15;
    int tbase = b * L_SEQ + c * LC;
    for (int t0 = 0; t0 < LC; t0 += 32) {
        __syncthreads();
#pragma unroll
        for (int jj = 0; jj < 2; ++jj) {
            int tt = jj * 16 + tt0;
            size_t trow = (size_t)(tbase + t0 + tt);
            s_dlt[tt][cc] = (float)delta[trow * DI_DIM + d0 + cc];
            s_u[tt][cc]   = (float)u_bf[trow * DI_DIM + d0 + cc];
            s_B[tt][cc]   = xdbl[trow * 96 + 64 + cc];
        }
        __syncthreads();
#pragma unroll
        for (int t = 0; t < 32; ++t) {
            float dlt = s_dlt[t][dl];
            float dA  = __expf(dlt * Ac);
            h = fmaf(dA, h, dlt * s_B[t][n] * s_u[t][dl]);
            P *= dA;
        }
    }
    size_t oi = (((size_t)(b * NC + c) * DI_DIM) + d) * NS_DIM + n;
    Pbuf[oi] = P;
    Sbuf[oi] = h;
}

// Phase C with fused chunk-prefix combine.
__global__ __launch_bounds__(256) void scan_phase_c(
        const bf16* __restrict__ delta, const float* __restrict__ xdbl,
        const bf16* __restrict__ u_bf, const bf16* __restrict__ xz,
        const float* __restrict__ A_log, const float* __restrict__ D_par,
        const float* __restrict__ Pbuf, const float* __restrict__ Sbuf,
        bf16* __restrict__ y)
{
    int tid = threadIdx.x;
    int c   = blockIdx.x & (NC - 1);
    int dblk= (blockIdx.x >> 3) & 127;
    int b   = blockIdx.x >> 10;
    int d0  = dblk << 4;
    int n = tid & 15, dl = tid >> 4;
    int d = d0 + dl;
    float Ac = -expf(A_log[(size_t)d * NS_DIM + n]);
    float Dp = D_par[d];
    float h = 0.0f;
    for (int cp = 0; cp < c; ++cp) {
        size_t oi = (((size_t)(b * NC + cp) * DI_DIM) + d) * NS_DIM + n;
        h = fmaf(Pbuf[oi], h, Sbuf[oi]);
    }
    __shared__ float s_dlt[32][16], s_u[32][16], s_res[32][16], s_B[32][16], s_C[32][16];
    __shared__ bf16  s_y[32][16];
    int tt0 = tid >> 4, cc = tid & 15;
    int tbase = b * L_SEQ + c * LC;
    for (int t0 = 0; t0 < LC; t0 += 32) {
        __syncthreads();
#pragma unroll
        for (int jj = 0; jj < 2; ++jj) {
            int tt = jj * 16 + tt0;
            size_t trow = (size_t)(tbase + t0 + tt);
            s_dlt[tt][cc] = (float)delta[trow * DI_DIM + d0 + cc];
            s_u[tt][cc]   = (float)u_bf[trow * DI_DIM + d0 + cc];
            s_res[tt][cc] = (float)xz[trow * (2 * DI_DIM) + DI_DIM + d0 + cc];
            s_B[tt][cc]   = xdbl[trow * 96 + 64 + cc];
            s_C[tt][cc]   = xdbl[trow * 96 + 80 + cc];
        }
        __syncthreads();
#pragma unroll
        for (int t = 0; t < 32; ++t) {
            float dlt = s_dlt[t][dl];
            float uu  = s_u[t][dl];
            float dA  = __expf(dlt * Ac);
            float dBu = dlt * s_B[t][n] * uu;
            h = fmaf(dA, h, dBu);
            float yp = h * s_C[t][n];
            yp += __shfl_xor(yp, 1);
            yp += __shfl_xor(yp, 2);
            yp += __shfl_xor(yp, 4);
            yp += __shfl_xor(yp, 8);
            if (n == 0) {
                float res = s_res[t][dl];
                float yv  = fmaf(uu, Dp, yp) * (res / (1.0f + __expf(-res)));
                s_y[t][dl] = (bf16)yv;
            }
        }
        __syncthreads();
#pragma unroll
        for (int jj = 0; jj < 2; ++jj) {
            int tt = jj * 16 + tt0;
            size_t trow = (size_t)(tbase + t0 + tt);
            y[trow * DI_DIM + d0 + cc] = s_y[tt][cc];
        }
    }
}

// ---------------- per-token online logsumexp + NLL + loss atomic (single pass) ----------------
__global__ void lse_nll_kernel(const float* __restrict__ logits, const int* __restrict__ targets,
                               float* __restrict__ lossp)
{
    int t = blockIdx.x, tid = threadIdx.x;
    const f32x4* row = (const f32x4*)(logits + (size_t)t * V_DIM);
    float m = -1e30f, s = 0.0f;
    for (int i = tid; i < V_DIM / 4; i += 256) {
        f32x4 v = row[i];
        float m4 = fmaxf(fmaxf(v[0], v[1]), fmaxf(v[2], v[3]));
        if (m4 > m) { s *= __expf(m - m4); m = m4; }
        s += __expf(v[0] - m) + __expf(v[1] - m) + __expf(v[2] - m) + __expf(v[3] - m);
    }
#pragma unroll
    for (int off = 1; off < 64; off <<= 1) {
        float mo = __shfl_xor(m, off), so = __shfl_xor(s, off);
        float nm = fmaxf(m, mo);
        s = s * __expf(m - nm) + so * __expf(mo - nm);
        m = nm;
    }
    __shared__ float pm[4], ps2[4];
    if ((tid & 63) == 0) { pm[tid >> 6] = m; ps2[tid >> 6] = s; }
    __syncthreads();
    if (tid == 0) {
        float M = fmaxf(fmaxf(pm[0], pm[1]), fmaxf(pm[2], pm[3]));
        float S = ps2[0] * __expf(pm[0] - M) + ps2[1] * __expf(pm[1] - M)
                + ps2[2] * __expf(pm[2] - M) + ps2[3] * __expf(pm[3] - M);
        int tg = targets[t];
        if (tg >= 0) {
            float v = (M + logf(S)) - logits[(size_t)t * V_DIM + tg];
            atomicAdd(lossp, v * (1.0f / NTOK));
        }
    }
}

// ---------------- host launcher ----------------
extern "C" void kernel_launch(void* const* d_in, const int* in_sizes, int n_in,
                              void* d_out, int out_size, void* d_ws, size_t ws_size,
                              hipStream_t stream)
{
    const int*   ids   = (const int*)d_in[0];
    const int*   tgt   = (const int*)d_in[1];
    const float* emb   = (const float*)d_in[2];
    const float* ln_w  = (const float*)d_in[3];
    const float* ln_b  = (const float*)d_in[4];
    const float* inw   = (const float*)d_in[5];
    const float* convw = (const float*)d_in[6];
    const float* convb = (const float*)d_in[7];
    const float* xw    = (const float*)d_in[8];
    const float* dtw   = (const float*)d_in[9];
    const float* dtb   = (const float*)d_in[10];
    const float* alog  = (const float*)d_in[11];
    const float* dpar  = (const float*)d_in[12];
    const float* outw  = (const float*)d_in[13];
    const float* flnw  = (const float*)d_in[14];
    const float* flnb  = (const float*)d_in[15];
    float* logits = (float*)d_out;
    float* lossp  = logits + (size_t)NTOK * V_DIM;

    const size_t INW_L  = (size_t)2 * DI_DIM * E_DIM;
    const size_t OUTW_L = (size_t)E_DIM * DI_DIM;
    const size_t DTW_L  = (size_t)DI_DIM * DTR_DIM;

    char* wsp = (char*)d_ws;
    size_t off = 0;
    auto alloc = [&](size_t bytes) -> void* {
        void* p = wsp + off;
        off += (bytes + 255) & ~(size_t)255;
        return p;
    };
    bf16*  emb_bf  = (bf16*)alloc((size_t)V_DIM * E_DIM * 2);
    float* x       = (float*)alloc((size_t)NTOK * E_DIM * 4);
    bf16*  h_bf    = (bf16*)alloc((size_t)NTOK * E_DIM * 2);
    bf16*  xzb     = (bf16*)alloc((size_t)NTOK * 2 * DI_DIM * 2);
    bf16*  u_bf    = (bf16*)alloc((size_t)NTOK * DI_DIM * 2);
    float* xdbl    = (float*)alloc((size_t)NTOK * 96 * 4);
    float* xpart   = (float*)alloc((size_t)2 * NTOK * 128 * 4);     // 1 MB
    bf16*  dt_bf   = (bf16*)alloc((size_t)NTOK * DTR_DIM * 2);
    bf16*  deltab  = (bf16*)alloc((size_t)NTOK * DI_DIM * 2);
    bf16*  y_bf    = (bf16*)alloc((size_t)NTOK * DI_DIM * 2);
    bf16*  xf_bf   = (bf16*)alloc((size_t)NTOK * E_DIM * 2);
    float* Pbuf    = (float*)alloc((size_t)NBATCH * NC * DI_DIM * NS_DIM * 4);
    float* Sbuf    = (float*)alloc((size_t)NBATCH * NC * DI_DIM * NS_DIM * 4);
    size_t base = off;
    size_t big_need = base + (((size_t)NL_DIM * INW_L * 2 + 255) & ~(size_t)255)
                           + (((size_t)NL_DIM * OUTW_L * 2 + 255) & ~(size_t)255)
                           + (((size_t)NL_DIM * DTW_L * 2 + 255) & ~(size_t)255);
    bool big = (big_need <= ws_size);
    bf16* winl; bf16* woutl; bf16* wdtl;
    if (big) {
        winl  = (bf16*)alloc((size_t)NL_DIM * INW_L * 2);
        woutl = (bf16*)alloc((size_t)NL_DIM * OUTW_L * 2);
        wdtl  = (bf16*)alloc((size_t)NL_DIM * DTW_L * 2);
    } else {
        winl  = (bf16*)alloc(INW_L * 2);
        woutl = (bf16*)alloc(OUTW_L * 2);
        wdtl  = (bf16*)alloc(DTW_L * 2);
    }
    if (off > ws_size) return;

    hipMemsetAsync(lossp, 0, sizeof(float), stream);
    {
        int n4 = (int)((size_t)V_DIM * E_DIM / 4);
        cast_f32_to_bf16<<<4096, 256, 0, stream>>>(emb, emb_bf, n4);
    }
    if (big) {
        cast3_kernel<<<4096, 256, 0, stream>>>(
            inw,  winl,  (int)((size_t)NL_DIM * INW_L / 4),
            outw, woutl, (int)((size_t)NL_DIM * OUTW_L / 4),
            dtw,  wdtl,  (int)((size_t)NL_DIM * DTW_L / 4));
    }
    embed_kernel<<<NTOK, 256, 0, stream>>>(ids, emb, x);

    for (int l = 0; l < NL_DIM; ++l) {
        const bf16* wi = big ? winl  + (size_t)l * INW_L  : winl;
        const bf16* wo = big ? woutl + (size_t)l * OUTW_L : woutl;
        const bf16* wd = big ? wdtl  + (size_t)l * DTW_L  : wdtl;
        if (!big) {
            cast3_kernel<<<2048, 256, 0, stream>>>(
                inw  + (size_t)l * INW_L,  winl,  (int)(INW_L / 4),
                outw + (size_t)l * OUTW_L, woutl, (int)(OUTW_L / 4),
                dtw  + (size_t)l * DTW_L,  wdtl,  (int)(DTW_L / 4));
        }
        ln_kernel<<<NTOK, 256, 0, stream>>>(x, ln_w + l * E_DIM, ln_b + l * E_DIM, h_bf);
        // xz[1024,4096] = h @ in_w^T  (bf16 out, BK=32, dbuf+counted vmcnt)
        launch_gemm<128, 64, 32, 4>(h_bf, wi, xzb, NTOK, 2 * DI_DIM, E_DIM,
                                    E_DIM, E_DIM, 2 * DI_DIM, nullptr, stream);
        // fused conv+silu+x_proj  (k-split x2: 512 blocks) + merge
        cxk_kernel<<<NTOK / 2, 256, 0, stream>>>(
            xzb, convw + (size_t)l * DI_DIM * DC_DIM, convb + (size_t)l * DI_DIM,
            xw + (size_t)l * 96 * DI_DIM, xpart, u_bf);
        xmerge_kernel<<<NTOK * 96 / 256, 256, 0, stream>>>(xpart, xdbl, dt_bf);
        // delta = softplus(dt @ dtw^T + dtb) (bf16 out)
        launch_gemm<64, 64, 32, 2>(dt_bf, wd, deltab, NTOK, DI_DIM, DTR_DIM,
                                   DTR_DIM, DTR_DIM, DI_DIM, dtb + (size_t)l * DI_DIM, stream);
        scan_phase_a<<<NBATCH * (DI_DIM / 16) * NC, 256, 0, stream>>>(
            deltab, xdbl, u_bf, alog + (size_t)l * DI_DIM * NS_DIM, Pbuf, Sbuf);
        scan_phase_c<<<NBATCH * (DI_DIM / 16) * NC, 256, 0, stream>>>(
            deltab, xdbl, u_bf, xzb, alog + (size_t)l * DI_DIM * NS_DIM,
            dpar + (size_t)l * DI_DIM, Pbuf, Sbuf, y_bf);
        // x += y @ out_w^T  (split-K 8x -> 512 blocks, 2/CU)
        launch_gemm<128, 128, 32, 5, 8>(y_bf, wo, x, NTOK, E_DIM, DI_DIM,
                                        DI_DIM, DI_DIM, E_DIM, nullptr, stream);
    }
    ln_kernel<<<NTOK, 256, 0, stream>>>(x, flnw, flnb, xf_bf);
    // logits = x_f @ emb^T  (256x256 8-wave, BK=64 dbuf, counted vmcnt — measured best)
    gemm256_logits<<<512, 512, 0, stream>>>(xf_bf, emb_bf, logits);
    lse_nll_kernel<<<NTOK, 256, 0, stream>>>(logits, tgt, lossp);
}